// Round 2
// 409.067 us; speedup vs baseline: 1.0702x; 1.0702x over previous
//
#include <hip/hip_runtime.h>
#include <stdint.h>

typedef __attribute__((ext_vector_type(8))) short short8;
typedef __attribute__((ext_vector_type(4))) short s16x4;
typedef __attribute__((ext_vector_type(4))) float f32x4;
typedef __attribute__((ext_vector_type(2))) float f32x2;
typedef __attribute__((ext_vector_type(4))) uint32_t uint32x4;

#define RES 56
#define NCH 256
#define SW 392     // valid tokens per window (56*7)
#define SP 416     // padded V^T token pitch

// LDS layout (bytes), total 62720 (<64KB -> 2 blocks/CU)
#define KP_OFF   0        // K panels: 4 x [400][8 shorts] = 25600 B (conflict-free b128 r/w)
#define VT_OFF   25600    // V^T bf16 [d(32)][tok(416)], tok ^= (d&12)<<1 swizzle = 26624 B
#define WB_OFF   52224    // conv w [9][32] f32
#define BB_OFF   53376    // bias [32] f32
#define SC_OFF   53504    // per-wave lepe scratch [32][18] f32 = 2304 B x 4 waves
#define SMEM_SZ  62720

__device__ __forceinline__ uint32_t cvtpk(float lo, float hi) {   // RNE pack: lo->bits[15:0], hi->bits[31:16]
    uint32_t r;
    asm("v_cvt_pk_bf16_f32 %0, %1, %2" : "=v"(r) : "v"(lo), "v"(hi));
    return r;
}
__device__ __forceinline__ float bf2f(short s) {
    return __uint_as_float(((uint32_t)(uint16_t)s) << 16);
}

__global__ __launch_bounds__(256, 2) void lepe_attn_kernel(
    const float* __restrict__ qg, const float* __restrict__ kg,
    const float* __restrict__ vg, const float* __restrict__ wg,
    const float* __restrict__ bg, float* __restrict__ outg)
{
    __shared__ __align__(16) char smem[SMEM_SZ];
    short* kpan = (short*)(smem + KP_OFF);
    short* vtb  = (short*)(smem + VT_OFF);
    float* wbuf = (float*)(smem + WB_OFF);
    float* bbuf = (float*)(smem + BB_OFF);

    const int tid  = threadIdx.x;
    const int lane = tid & 63;
    const int wv   = tid >> 6;
    const int col  = lane & 15;   // MFMA n/m index
    const int g    = lane >> 4;   // MFMA quad

    const int h  = blockIdx.x & 7;        // head
    const int bw = blockIdx.x >> 3;       // window id
    const int s  = bw & 7;                // stripe index
    const int b  = bw >> 3;               // batch

    const int cb = h * 32;                // channel base
    const int tb = b * (RES * RES);       // token base

    // ---- stage conv weights + bias ----
    for (int i = tid; i < 288; i += 256)
        wbuf[i] = wg[(i >> 5) * NCH + cb + (i & 31)];
    if (tid < 32)
        bbuf[tid] = bg[cb + tid];

    // ---- stage K (panel-major, conflict-free) and V^T (fine XOR swizzle) as bf16 ----
    #pragma unroll
    for (int p0 = 0; p0 < 1792; p0 += 256) {
        int idx = p0 + tid;
        if (idx < 1664) {                       // 416 toks * 4 hd-groups
            int tok = idx >> 2;
            int hd8 = (idx & 3) << 3;
            f32x4 ka = {0.f,0.f,0.f,0.f}, kb2 = ka, va = ka, vb = ka;
            if (tok < SW) {
                int y  = (tok * 9363) >> 16;    // tok/7 exact for tok<1871
                int xx = tok - y * 7;
                int n  = y * RES + s * 7 + xx;
                int off = (tb + n) * NCH + cb + hd8;
                ka  = *(const f32x4*)(kg + off);
                kb2 = *(const f32x4*)(kg + off + 4);
                va  = *(const f32x4*)(vg + off);
                vb  = *(const f32x4*)(vg + off + 4);
            }
            if (tok < 400) {                    // K panels only hold 400 rows
                uint32x4 kv;
                kv[0] = cvtpk(ka[0],  ka[1]);
                kv[1] = cvtpk(ka[2],  ka[3]);
                kv[2] = cvtpk(kb2[0], kb2[1]);
                kv[3] = cvtpk(kb2[2], kb2[3]);
                *(uint32x4*)(kpan + (hd8 >> 3) * 3200 + tok * 8) = kv;  // 16B ds_write_b128
            }
            // V^T scatter: row d = hd8+j, slot = tok ^ ((d&12)<<1); bijective per d.
            uint32_t v01 = cvtpk(va[0], va[1]);
            uint32_t v23 = cvtpk(va[2], va[3]);
            uint32_t v45 = cvtpk(vb[0], vb[1]);
            uint32_t v67 = cvtpk(vb[2], vb[3]);
            int swl = (hd8 & 12) << 1;          // d&12 for j=0..3
            int ta  = tok ^ swl;
            int tc  = tok ^ (swl + 8);          // d&12 for j=4..7 is +4 -> sw +8
            short* vr = vtb + hd8 * SP;
            vr[ta] = (short)v01;         vr += SP;
            vr[ta] = (short)(v01 >> 16); vr += SP;
            vr[ta] = (short)v23;         vr += SP;
            vr[ta] = (short)(v23 >> 16); vr += SP;
            vr[tc] = (short)v45;         vr += SP;
            vr[tc] = (short)(v45 >> 16); vr += SP;
            vr[tc] = (short)v67;         vr += SP;
            vr[tc] = (short)(v67 >> 16);
        }
    }
    __syncthreads();

    const float SCL = 0.17677669529663688f * 1.4426950408889634f; // hd^-0.5 * log2(e)
    const f32x4 zero4 = {0.f, 0.f, 0.f, 0.f};
    const float NINF = -__builtin_inff();
    const short* kg0 = kpan + g * 3200 + col * 8;   // panel g, row col; kt walks +256B imm

    for (int qt = wv; qt < 25; qt += 4) {
        // ---- Q B-fragment from global (lane: q = col, hd = 8g..8g+7) ----
        int qrow = (qt << 4) + col;
        int tq = qrow < SW ? qrow : SW - 1;
        int yq = (tq * 9363) >> 16;
        int nq = yq * RES + s * 7 + (tq - yq * 7);
        short8 qf;
        {
            int qoff = (tb + nq) * NCH + cb + (g << 3);
            f32x4 qa = *(const f32x4*)(qg + qoff);
            f32x4 qb = *(const f32x4*)(qg + qoff + 4);
            union { uint32_t u[4]; short8 s8; } qu;
            qu.u[0] = cvtpk(qa[0]*SCL, qa[1]*SCL);
            qu.u[1] = cvtpk(qa[2]*SCL, qa[3]*SCL);
            qu.u[2] = cvtpk(qb[0]*SCL, qb[1]*SCL);
            qu.u[3] = cvtpk(qb[2]*SCL, qb[3]*SCL);
            qf = qu.s8;
        }

        // ---- S^T = K * Q^T : lane holds S^T[tok=kt*16+4g+r][q=col] ----
        f32x4 Sf[25];
        #pragma unroll
        for (int kt = 0; kt < 25; ++kt) {
            short8 kf = *(const short8*)(kg0 + kt * 128);   // conflict-free panel read
            Sf[kt] = __builtin_amdgcn_mfma_f32_16x16x32_bf16(kf, qf, zero4, 0, 0, 0);
        }
        #pragma unroll
        for (int r = 0; r < 4; ++r) Sf[24][r] = (g >= 2) ? NINF : Sf[24][r]; // toks 392..399

        // ---- softmax over tok (fixed q per lane) ----
        float m = NINF;
        #pragma unroll
        for (int kt = 0; kt < 25; ++kt) {
            #pragma unroll
            for (int r = 0; r < 4; ++r) m = fmaxf(m, Sf[kt][r]);
        }
        m = fmaxf(m, __shfl_xor(m, 16));
        m = fmaxf(m, __shfl_xor(m, 32));

        uint32_t pk[25][2];
        float l = 0.f;
        #pragma unroll
        for (int kt = 0; kt < 25; ++kt) {
            float p0 = exp2f(Sf[kt][0] - m);
            float p1 = exp2f(Sf[kt][1] - m);
            float p2 = exp2f(Sf[kt][2] - m);
            float p3 = exp2f(Sf[kt][3] - m);
            // truncate-pack pairs to bf16 (v_perm), sum the truncated values for consistency
            uint32_t u01 = __builtin_amdgcn_perm(__float_as_uint(p1), __float_as_uint(p0), 0x07060302u);
            uint32_t u23 = __builtin_amdgcn_perm(__float_as_uint(p3), __float_as_uint(p2), 0x07060302u);
            pk[kt][0] = u01; pk[kt][1] = u23;
            l += __uint_as_float(u01 << 16) + __uint_as_float(u01 & 0xffff0000u)
               + __uint_as_float(u23 << 16) + __uint_as_float(u23 & 0xffff0000u);
        }
        l += __shfl_xor(l, 16);
        l += __shfl_xor(l, 32);
        float invl = 1.0f / l;

        // ---- O^T = V^T * P^T via 16x16x16 MFMA: P B-frag comes straight from pk ----
        // B-frag of 16x16x16: B[k=4g+j][n=col] == pk[kt] layout exactly (no LDS round-trip).
        f32x4 O0a = zero4, O0b = zero4, O1a = zero4, O1b = zero4;
        const short* vl = vtb + col * SP;          // d = col
        const short* vh = vl + 16 * SP;            // d = col+16 (same swizzle: (col+16)&12 == col&12)
        const int vsw = (col & 12) << 1;
        const int gof = g << 2;
        #pragma unroll
        for (int kt = 0; kt < 25; ++kt) {
            int tokx = ((kt << 4) + gof) ^ vsw;    // conflict-free b64 read
            s16x4 a0 = *(const s16x4*)(vl + tokx);
            s16x4 a1 = *(const s16x4*)(vh + tokx);
            union { uint32_t u[2]; s16x4 s4; } pu;
            pu.u[0] = pk[kt][0]; pu.u[1] = pk[kt][1];
            if (kt & 1) {
                O0b = __builtin_amdgcn_mfma_f32_16x16x16bf16_1k(a0, pu.s4, O0b, 0, 0, 0);
                O1b = __builtin_amdgcn_mfma_f32_16x16x16bf16_1k(a1, pu.s4, O1b, 0, 0, 0);
            } else {
                O0a = __builtin_amdgcn_mfma_f32_16x16x16bf16_1k(a0, pu.s4, O0a, 0, 0, 0);
                O1a = __builtin_amdgcn_mfma_f32_16x16x16bf16_1k(a1, pu.s4, O1a, 0, 0, 0);
            }
        }

        // ---- LePE for this tile's 16 tokens, via V^T in LDS ----
        float* scr = (float*)(smem + SC_OFF + wv * 2304);
        {
            int d = lane >> 1, half = lane & 1;
            int t0 = (qt << 4) + (half << 3);
            int dsw = (d & 12) << 1;
            const short* vrow = vtb + d * SP;
            float vals[24];
            #pragma unroll
            for (int kk = 0; kk < 3; ++kk) {
                int t8 = t0 - 8 + (kk << 3);
                if (t8 < 0) t8 = 0;                          // garbage but always masked
                short8 bv = *(const short8*)(vrow + (t8 ^ dsw));
                #pragma unroll
                for (int j = 0; j < 8; ++j) vals[kk * 8 + j] = bf2f(bv[j]);
            }
            float wr[9];
            #pragma unroll
            for (int t9 = 0; t9 < 9; ++t9) wr[t9] = wbuf[t9 * 32 + d];
            float bs = bbuf[d];
            float o[8];
            #pragma unroll
            for (int i = 0; i < 8; ++i) {
                int t = t0 + i;
                int yy = (t * 9363) >> 16;
                int xxi = t - yy * 7;
                float mlft = (xxi == 0) ? 0.f : 1.f;
                float mrgt = (xxi == 6) ? 0.f : 1.f;
                float mu   = (t >= 7)   ? 1.f : 0.f;
                float md   = (t <= 384) ? 1.f : 0.f;
                float top = wr[0]*(vals[i]*mlft)    + wr[1]*vals[i+1]  + wr[2]*(vals[i+2]*mrgt);
                float mid = wr[3]*(vals[i+7]*mlft)  + wr[4]*vals[i+8]  + wr[5]*(vals[i+9]*mrgt);
                float bot = wr[6]*(vals[i+14]*mlft) + wr[7]*vals[i+15] + wr[8]*(vals[i+16]*mrgt);
                o[i] = bs + mid + mu * top + md * bot;
            }
            #pragma unroll
            for (int mm = 0; mm < 4; ++mm) {
                f32x2 pr = {o[2*mm], o[2*mm+1]};
                *(f32x2*)(scr + d * 18 + (half << 3) + 2 * mm) = pr;  // pitch 18 f32
            }
        }

        // ---- normalize, add LePE, store ----
        f32x4 r0, r1;
        #pragma unroll
        for (int r = 0; r < 4; ++r) {
            r0[r] = (O0a[r] + O0b[r]) * invl + scr[(4 * g + r) * 18 + col];
            r1[r] = (O1a[r] + O1b[r]) * invl + scr[(16 + 4 * g + r) * 18 + col];
        }
        if (qrow < SW) {
            float* op = outg + (tb + nq) * NCH + cb + (g << 2);
            *(f32x4*)op = r0;
            *(f32x4*)(op + 16) = r1;
        }
    }
}

extern "C" void kernel_launch(void* const* d_in, const int* in_sizes, int n_in,
                              void* d_out, int out_size, void* d_ws, size_t ws_size,
                              hipStream_t stream) {
    const float* q  = (const float*)d_in[0];
    const float* k  = (const float*)d_in[1];
    const float* v  = (const float*)d_in[2];
    const float* wc = (const float*)d_in[3];
    const float* bc = (const float*)d_in[4];
    float* out = (float*)d_out;
    hipLaunchKernelGGL(lepe_attn_kernel, dim3(2048), dim3(256), 0, stream,
                       q, k, v, wc, bc, out);
}